// Round 2
// baseline (119.675 us; speedup 1.0000x reference)
//
#include <hip/hip_runtime.h>

// SplineActivation: out[b,d] = sum_k basis_k(x[b,d]) * coeffs[d,k]
// Uniform cubic B-spline as per-cell Horner cubic:
//   out = p0 + s*(p1 + s*(p2 + s*p3)), c = clamp(floor(u),0,3), s = u-c.
//
// R1 -> R2 changes:
//  * ROWS 16 -> 64: grid = 1024 blocks = exactly 4 resident/CU (27.6 KB LDS
//    each), one dispatch round; staging amortized over 128 KB of streaming.
//  * Coalesced staging: the block's coeff tile is 1792 CONTIGUOUS floats
//    (rows dbase..dbase+255, row-major (4096,7)); load as float4 into raw
//    LDS, repack from there. Replaces 7 scattered scalar global loads/lane.
//  * Software-pipelined main loop: 4 rows in flight, prefetch next group
//    before computing current; nontemporal load/store on the x/out streams.
//  * Gather keeps the transposed slot map: slot l + 64*j holds d-local
//    dl = 4*l + j, stride 20 words -> bank-quad step 5 (gcd(5,8)=1),
//    conflict-free ds_read_b128.

typedef float f4v __attribute__((ext_vector_type(4)));

#define D     4096
#define B     4096
#define NB    7
#define DTILE 256
#define ROWS  64

constexpr int NDT    = D / DTILE;   // 16 d-tiles
constexpr int NRT    = B / ROWS;    // 64 row-tiles
constexpr int STRIDE = 20;          // words per slot: 4 cells * 4 words + 4 pad

__global__ __launch_bounds__(256, 4) void
spline_act_kernel(const float* __restrict__ x,
                  const float* __restrict__ coeffs,
                  float* __restrict__ out) {
    __shared__ float sc[DTILE * STRIDE];   // 20480 B packed Horner coeffs
    __shared__ float raw[DTILE * NB];      // 7168 B raw staging

    const int bid   = blockIdx.x;
    const int dt    = bid & (NDT - 1);
    const int rowt  = bid >> 4;
    const int dbase = dt * DTILE;
    const int t     = threadIdx.x;

    // ---- Stage: coalesced float4 loads of the contiguous 7 KB coeff tile.
    {
        const f4v* c4 = reinterpret_cast<const f4v*>(coeffs + (size_t)dbase * NB);
        f4v* r4 = reinterpret_cast<f4v*>(raw);
        r4[t] = c4[t];                                  // 256 float4
        if (t < (DTILE * NB / 4) - 256)                 // + 192 float4 = 448
            r4[256 + t] = c4[256 + t];
        __syncthreads();

        // Thread t owns LDS slot t = l + 64*j  ->  d-local dl = 4*l + j.
        const int dl = 4 * (t & 63) + (t >> 6);
        float cr[NB];
#pragma unroll
        for (int k = 0; k < NB; ++k) cr[k] = raw[dl * NB + k];

        const float k6 = 1.0f / 6.0f;
        float* bp = &sc[t * STRIDE];
#pragma unroll
        for (int c = 0; c < 4; ++c) {
            float A  = cr[c];
            float Bv = cr[c + 1];
            float C  = cr[c + 2];
            float Dv = cr[c + 3];
            f4v p;
            p[0] = (A + 4.0f * Bv + C) * k6;
            p[1] = (C - A) * 0.5f;
            p[2] = (A + C) * 0.5f - Bv;
            p[3] = (Dv - A + 3.0f * (Bv - C)) * k6;
            *reinterpret_cast<f4v*>(bp + 4 * c) = p;
        }
        __syncthreads();
    }

    const int pos  = t & 63;      // float4 column within the 256-d tile (= lane)
    const int rsub = t >> 6;      // which of 4 concurrent rows
    const int lbase = pos * STRIDE;

    const f4v* x4 = reinterpret_cast<const f4v*>(x);
    f4v*       o4 = reinterpret_cast<f4v*>(out);

    const int rstep = 4 * (D / 4);                       // 4 rows in float4s
    int idx = (rowt * ROWS + rsub) * (D / 4) + (dbase >> 2) + pos;

    auto process = [&](f4v xv, int iidx) {
        f4v r;
#pragma unroll
        for (int j = 0; j < 4; ++j) {
            float u  = fmaf(xv[j], 2.0f, 2.0f);          // cell coord in [0,4)
            float cf = floorf(u);
            cf = fminf(fmaxf(cf, 0.0f), 3.0f);           // v_med3_f32
            float s  = u - cf;
            int   c  = (int)cf;
            const f4v cv = *reinterpret_cast<const f4v*>(
                &sc[lbase + j * (64 * STRIDE) + (c << 2)]);
            r[j] = fmaf(fmaf(fmaf(cv[3], s, cv[2]), s, cv[1]), s, cv[0]);
        }
        __builtin_nontemporal_store(r, &o4[iidx]);
    };

    // ---- Software-pipelined stream: 4 rows in flight, prefetch next 4.
    f4v a0 = __builtin_nontemporal_load(&x4[idx + 0 * rstep]);
    f4v a1 = __builtin_nontemporal_load(&x4[idx + 1 * rstep]);
    f4v a2 = __builtin_nontemporal_load(&x4[idx + 2 * rstep]);
    f4v a3 = __builtin_nontemporal_load(&x4[idx + 3 * rstep]);

#pragma unroll
    for (int g = 0; g < 4; ++g) {
        f4v b0, b1, b2, b3;
        const int nidx = idx + 4 * rstep;
        if (g < 3) {
            b0 = __builtin_nontemporal_load(&x4[nidx + 0 * rstep]);
            b1 = __builtin_nontemporal_load(&x4[nidx + 1 * rstep]);
            b2 = __builtin_nontemporal_load(&x4[nidx + 2 * rstep]);
            b3 = __builtin_nontemporal_load(&x4[nidx + 3 * rstep]);
        } else {
            b0 = a0; b1 = a1; b2 = a2; b3 = a3;
        }
        process(a0, idx + 0 * rstep);
        process(a1, idx + 1 * rstep);
        process(a2, idx + 2 * rstep);
        process(a3, idx + 3 * rstep);
        a0 = b0; a1 = b1; a2 = b2; a3 = b3;
        idx = nidx;
    }
}

extern "C" void kernel_launch(void* const* d_in, const int* in_sizes, int n_in,
                              void* d_out, int out_size, void* d_ws, size_t ws_size,
                              hipStream_t stream) {
    const float* x      = (const float*)d_in[0];   // (4096, 4096) fp32
    const float* coeffs = (const float*)d_in[1];   // (4096, 7) fp32
    float* out          = (float*)d_out;           // (4096, 4096) fp32

    const int grid = NDT * NRT;   // 1024 blocks x 256 threads
    spline_act_kernel<<<grid, 256, 0, stream>>>(x, coeffs, out);
}

// Round 3
// 116.833 us; speedup vs baseline: 1.0243x; 1.0243x over previous
//
#include <hip/hip_runtime.h>

// SplineActivation: out[b,d] = sum_k basis_k(x[b,d]) * coeffs[d,k]
// Uniform cubic B-spline as per-cell Horner cubic:
//   out = p0 + s*(p1 + s*(p2 + s*p3)), c = clamp(floor(u),0,3), s = u-c.
//
// R2 -> R3: restore the 8-blocks/CU occupancy point (R2's 4/CU halved TLP
// and cost +7us). Keep only occupancy-neutral wins:
//  * ROWS 32, grid 2048 = exactly one residency round (8 blocks/CU, 32
//    waves/CU), staging amortized 2x vs R1, no second-round bubble.
//  * Coalesced staging, LDS kept at 20 KB by ALIASING the raw tile into sc:
//    float4-load the contiguous 7 KB coeff tile into sc, bounce each
//    thread's 7 coeffs through registers, sync, overwrite sc with the
//    packed per-cell Horner windows.
//  * Plain loads/stores, no manual prefetch (R1-proven; compiler hoists
//    the 8 independent chains itself).
// Gather keeps the transposed slot map: slot l + 64*j holds d-local
// dl = 4*l + j, stride 20 words -> bank-quad step 5 (gcd(5,8)=1),
// conflict-free ds_read_b128.

typedef float f4v __attribute__((ext_vector_type(4)));

#define D     4096
#define B     4096
#define NB    7
#define DTILE 256
#define ROWS  32

constexpr int NDT    = D / DTILE;   // 16 d-tiles
constexpr int NRT    = B / ROWS;    // 128 row-tiles
constexpr int STRIDE = 20;          // words per slot: 4 cells * 4 words + 4 pad

__global__ __launch_bounds__(256, 8) void
spline_act_kernel(const float* __restrict__ x,
                  const float* __restrict__ coeffs,
                  float* __restrict__ out) {
    __shared__ float sc[DTILE * STRIDE];   // 20480 B (raw tile aliases this)

    const int bid   = blockIdx.x;
    const int dt    = bid & (NDT - 1);
    const int rowt  = bid >> 4;
    const int dbase = dt * DTILE;
    const int t     = threadIdx.x;

    // ---- Stage: coalesced float4 loads of the contiguous 7 KB coeff tile
    // into sc (raw layout), bounce to regs, then overwrite with packed.
    {
        const f4v* c4 = reinterpret_cast<const f4v*>(coeffs + (size_t)dbase * NB);
        f4v* r4 = reinterpret_cast<f4v*>(sc);
        r4[t] = c4[t];                                  // 256 float4
        if (t < (DTILE * NB / 4) - 256)                 // + 192 float4 = 448
            r4[256 + t] = c4[256 + t];
        __syncthreads();

        // Thread t owns LDS slot t = l + 64*j  ->  d-local dl = 4*l + j.
        const int dl = 4 * (t & 63) + (t >> 6);
        float cr[NB];
#pragma unroll
        for (int k = 0; k < NB; ++k) cr[k] = sc[dl * NB + k];
        __syncthreads();                                 // raw fully read

        const float k6 = 1.0f / 6.0f;
        float* bp = &sc[t * STRIDE];
#pragma unroll
        for (int c = 0; c < 4; ++c) {
            float A  = cr[c];
            float Bv = cr[c + 1];
            float C  = cr[c + 2];
            float Dv = cr[c + 3];
            f4v p;
            p[0] = (A + 4.0f * Bv + C) * k6;
            p[1] = (C - A) * 0.5f;
            p[2] = (A + C) * 0.5f - Bv;
            p[3] = (Dv - A + 3.0f * (Bv - C)) * k6;
            *reinterpret_cast<f4v*>(bp + 4 * c) = p;
        }
        __syncthreads();
    }

    const int pos   = t & 63;     // float4 column within the 256-d tile (= lane)
    const int rsub  = t >> 6;     // which of 4 concurrent rows
    const int lbase = pos * STRIDE;

    const f4v* x4 = reinterpret_cast<const f4v*>(x);
    f4v*       o4 = reinterpret_cast<f4v*>(out);

    const int rowbase = rowt * ROWS;

#pragma unroll
    for (int it = 0; it < ROWS / 4; ++it) {
        const int row = rowbase + it * 4 + rsub;
        const int idx = row * (D / 4) + (dbase >> 2) + pos;

        const f4v xv = x4[idx];
        f4v r;
#pragma unroll
        for (int j = 0; j < 4; ++j) {
            float u  = fmaf(xv[j], 2.0f, 2.0f);          // cell coord in [0,4)
            float cf = floorf(u);
            cf = fminf(fmaxf(cf, 0.0f), 3.0f);           // v_med3_f32
            float s  = u - cf;
            int   c  = (int)cf;
            const f4v cv = *reinterpret_cast<const f4v*>(
                &sc[lbase + j * (64 * STRIDE) + (c << 2)]);
            r[j] = fmaf(fmaf(fmaf(cv[3], s, cv[2]), s, cv[1]), s, cv[0]);
        }
        o4[idx] = r;
    }
}

extern "C" void kernel_launch(void* const* d_in, const int* in_sizes, int n_in,
                              void* d_out, int out_size, void* d_ws, size_t ws_size,
                              hipStream_t stream) {
    const float* x      = (const float*)d_in[0];   // (4096, 4096) fp32
    const float* coeffs = (const float*)d_in[1];   // (4096, 7) fp32
    float* out          = (float*)d_out;           // (4096, 4096) fp32

    const int grid = NDT * NRT;   // 2048 blocks x 256 threads
    spline_act_kernel<<<grid, 256, 0, stream>>>(x, coeffs, out);
}

// Round 4
// 114.281 us; speedup vs baseline: 1.0472x; 1.0223x over previous
//
#include <hip/hip_runtime.h>

// SplineActivation: out[b,d] = sum_k basis_k(x[b,d]) * coeffs[d,k]
// Uniform cubic B-spline, weight form:
//   w0=(1-s)^3/6, w1=(3s^3-6s^2+4)/6, w2=(-3s^3+3s^2+3s+1)/6, w3=s^3/6
//   out = w0*C[c] + w1*C[c+1] + w2*C[c+2] + w3*C[c+3], c=clamp(floor(u),0,3)
//
// R3 -> R4: ZERO LDS, ZERO barriers. R0-R3 showed every barrier/staging
// variant costs more than it saves; the block-start stage->sync->stream
// bubble is the unhidden cost. Here each thread owns 4 fixed d-columns
// (d = dbase + 4*pos + j) whose 7 coeffs each are 28 CONTIGUOUS floats
// (112 B, 16B-aligned): 7 dwordx4 loads into 28 VGPRs at block start,
// no sync, overlapped with the first x loads, L2-hit (coeffs = 112 KB,
// L2-resident). The data-dependent window gather is a branchless register
// select: 3 shared v_cmp + 12 v_cndmask per element (~36 VALU/elem total;
// per-SIMD VALU ~16K cyc << per-CU HBM floor ~51K cyc -> stays hidden).
// #pragma unroll 2 keeps VGPR ~55 (<=64) for full 8-waves/SIMD occupancy.

typedef float f4v __attribute__((ext_vector_type(4)));

#define D     4096
#define B     4096
#define NB    7
#define DTILE 256
#define ROWS  16

constexpr int NDT = D / DTILE;   // 16 d-tiles
constexpr int NRT = B / ROWS;    // 256 row-tiles

__global__ __launch_bounds__(256, 8) void
spline_act_kernel(const float* __restrict__ x,
                  const float* __restrict__ coeffs,
                  float* __restrict__ out) {
    const int bid   = blockIdx.x;
    const int dt    = bid & (NDT - 1);
    const int rowt  = bid >> 4;
    const int dbase = dt * DTILE;
    const int t     = threadIdx.x;
    const int pos   = t & 63;     // float4 column within the 256-d tile
    const int rsub  = t >> 6;     // which of 4 concurrent rows

    // ---- Per-thread coeffs: rows d0..d0+3 are 28 contiguous floats.
    const f4v* c4 = reinterpret_cast<const f4v*>(
        coeffs + (size_t)(dbase + 4 * pos) * NB);
    const f4v q0 = c4[0], q1 = c4[1], q2 = c4[2], q3 = c4[3],
              q4 = c4[4], q5 = c4[5], q6 = c4[6];

    // cr[j][k] = coeffs[d0+j][k]; all indexing below is compile-time.
    const float cr[4][NB] = {
        {q0[0], q0[1], q0[2], q0[3], q1[0], q1[1], q1[2]},
        {q1[3], q2[0], q2[1], q2[2], q2[3], q3[0], q3[1]},
        {q3[2], q3[3], q4[0], q4[1], q4[2], q4[3], q5[0]},
        {q5[1], q5[2], q5[3], q6[0], q6[1], q6[2], q6[3]},
    };

    const f4v* x4 = reinterpret_cast<const f4v*>(x);
    f4v*       o4 = reinterpret_cast<f4v*>(out);

    const int rowbase = rowt * ROWS;
    const float k6 = 1.0f / 6.0f;

#pragma unroll 2
    for (int it = 0; it < ROWS / 4; ++it) {
        const int row = rowbase + it * 4 + rsub;
        const int idx = row * (D / 4) + (dbase >> 2) + pos;

        const f4v xv = x4[idx];
        f4v r;
#pragma unroll
        for (int j = 0; j < 4; ++j) {
            float u  = fmaf(xv[j], 2.0f, 2.0f);      // cell coord in [0,4)
            float cf = floorf(u);
            cf = fminf(fmaxf(cf, 0.0f), 3.0f);       // v_med3_f32
            const float s = u - cf;

            const float* C = cr[j];
            const bool b0 = cf < 0.5f;               // c == 0
            const bool b1 = cf < 1.5f;               // c <= 1
            const bool b2 = cf < 2.5f;               // c <= 2
            const float t0 = b1 ? (b0 ? C[0] : C[1]) : (b2 ? C[2] : C[3]);
            const float t1 = b1 ? (b0 ? C[1] : C[2]) : (b2 ? C[3] : C[4]);
            const float t2 = b1 ? (b0 ? C[2] : C[3]) : (b2 ? C[4] : C[5]);
            const float t3 = b1 ? (b0 ? C[3] : C[4]) : (b2 ? C[5] : C[6]);

            const float omt = 1.0f - s;
            const float s2  = s * s;
            const float s3  = s2 * s;
            const float w0 = omt * omt * omt * k6;
            const float w1 = fmaf(3.0f, s3, fmaf(-6.0f, s2, 4.0f)) * k6;
            const float w2 = fmaf(-3.0f, s3,
                             fmaf(3.0f, s2, fmaf(3.0f, s, 1.0f))) * k6;
            const float w3 = s3 * k6;

            r[j] = fmaf(w0, t0, fmaf(w1, t1, fmaf(w2, t2, w3 * t3)));
        }
        o4[idx] = r;
    }
}

extern "C" void kernel_launch(void* const* d_in, const int* in_sizes, int n_in,
                              void* d_out, int out_size, void* d_ws, size_t ws_size,
                              hipStream_t stream) {
    const float* x      = (const float*)d_in[0];   // (4096, 4096) fp32
    const float* coeffs = (const float*)d_in[1];   // (4096, 7) fp32
    float* out          = (float*)d_out;           // (4096, 4096) fp32

    const int grid = NDT * NRT;   // 4096 blocks x 256 threads
    spline_act_kernel<<<grid, 256, 0, stream>>>(x, coeffs, out);
}